// Round 1
// baseline (52.054 us; speedup 1.0000x reference)
//
#include <hip/hip_runtime.h>

// Segmented histogram: out[g, c] = sum of node_weights[i] for i in
// [ptr[g], ptr[g+1]) with x[i] == c, for c < out_dim.
//
// One block per graph. 256-bin (out_dim) histogram in LDS, LDS atomics,
// then a coalesced write of the graph's row.

extern "C" __global__ void seg_hist_kernel(const int* __restrict__ x,
                                           const int* __restrict__ ptr,
                                           const float* __restrict__ w,
                                           float* __restrict__ out,
                                           int out_dim) {
    extern __shared__ float hist[];  // out_dim floats

    const int g = blockIdx.x;
    const int start = ptr[g];
    const int end = ptr[g + 1];

    // zero the LDS histogram
    for (int c = threadIdx.x; c < out_dim; c += blockDim.x) hist[c] = 0.0f;
    __syncthreads();

    // accumulate this graph's nodes
    for (int i = start + (int)threadIdx.x; i < end; i += (int)blockDim.x) {
        const int lbl = x[i];
        if ((unsigned)lbl < (unsigned)out_dim) {
            atomicAdd(&hist[lbl], w[i]);
        }
    }
    __syncthreads();

    // coalesced row write
    float* o = out + (size_t)g * (size_t)out_dim;
    for (int c = threadIdx.x; c < out_dim; c += blockDim.x) o[c] = hist[c];
}

extern "C" void kernel_launch(void* const* d_in, const int* in_sizes, int n_in,
                              void* d_out, int out_size, void* d_ws, size_t ws_size,
                              hipStream_t stream) {
    const int* x   = (const int*)d_in[0];
    const int* ptr = (const int*)d_in[1];
    const float* w = (const float*)d_in[2];
    float* out     = (float*)d_out;

    const int num_graphs = in_sizes[1] - 1;          // ptr has num_graphs+1 entries
    const int out_dim    = out_size / num_graphs;    // 256

    dim3 grid(num_graphs);
    dim3 block(256);
    size_t lds_bytes = (size_t)out_dim * sizeof(float);

    seg_hist_kernel<<<grid, block, lds_bytes, stream>>>(x, ptr, w, out, out_dim);
}